// Round 9
// baseline (173.426 us; speedup 1.0000x reference)
//
#include <hip/hip_runtime.h>
#include <hip/hip_bf16.h>
#include <stdint.h>

typedef short short8 __attribute__((ext_vector_type(8)));
typedef float f32x4 __attribute__((ext_vector_type(4)));

// Problem constants
constexpr int SEQ   = 2048;   // T
constexpr int DM    = 1024;   // model dim
constexpr int NHEAD = 16;
constexpr int HD    = 64;     // head dim
constexpr int LDQ   = 1152;   // QKV row stride: 1024 Q | 64 K | 64 V
constexpr int BATCH = 2;

__device__ __forceinline__ unsigned short f2bf(float f) {
    union { float f; uint32_t u; } v; v.f = f;
    uint32_t u = v.u;
    uint32_t r = (u + 0x7fffu + ((u >> 16) & 1u)) >> 16;
    return (unsigned short)r;
}

// async global->LDS, 16B per lane. LDS dest = wave-uniform base + lane*16.
typedef __attribute__((address_space(1))) const void gvoid_t;
typedef __attribute__((address_space(3))) void lvoid_t;
__device__ __forceinline__ void gload16(const void* g, void* l) {
    __builtin_amdgcn_global_load_lds((gvoid_t*)g, (lvoid_t*)l, 16, 0, 0);
}

// ---------------- cast x (fp32 -> bf16), vectorized ----------------
__global__ __launch_bounds__(256) void cast_x_kernel(
        const float* __restrict__ x, unsigned short* __restrict__ xb, int n) {
    int i = (blockIdx.x * 256 + threadIdx.x) * 4;
    if (i >= n) return;
    const float4 v = *(const float4*)(x + i);
    ushort4 o;
    o.x = f2bf(v.x); o.y = f2bf(v.y); o.z = f2bf(v.z); o.w = f2bf(v.w);
    *(ushort4*)(xb + i) = o;
}

// ---- fused weight prep: cast+transpose Wq,Wk,Wv,Wo in one launch ----
__global__ __launch_bounds__(256) void prep_w_kernel(
        const float* __restrict__ Wq, const float* __restrict__ Wk,
        const float* __restrict__ Wv, const float* __restrict__ Wo,
        unsigned short* __restrict__ wtq, unsigned short* __restrict__ wot) {
    __shared__ unsigned short tile[32][33];
    int z = blockIdx.z;
    const float* W; unsigned short* Wt; int C;
    if (z == 0)      { W = Wq; Wt = wtq;                              C = DM; }
    else if (z == 1) { W = Wk; Wt = wtq + (size_t)DM * DM;            C = HD; }
    else if (z == 2) { W = Wv; Wt = wtq + (size_t)(DM + HD) * DM;     C = HD; }
    else             { W = Wo; Wt = wot;                              C = DM; }
    int c0 = blockIdx.x * 32, r0 = blockIdx.y * 32;
    if (c0 >= C) return;
    int tx = threadIdx.x & 31, ty = threadIdx.x >> 5;  // ty 0..7
    for (int i = ty; i < 32; i += 8)
        tile[i][tx] = f2bf(W[(size_t)(r0 + i) * C + (c0 + tx)]);
    __syncthreads();
    for (int i = ty; i < 32; i += 8)
        Wt[(size_t)(c0 + i) * DM + (r0 + tx)] = tile[tx][i];
}

// ------------- GEMM: C[M,N] = A[M,K](bf16) @ Bt[N,K]^T(bf16) -------------
// 64x64 tile (qkv: 1152 blocks = 4.5/CU; out: 1024 = 4/CU). BK=64 staged
// via global_load_lds with (row&7) xor chunk swizzle (conflict-free b128
// fragment reads). Double-buffered. 4 waves in 2x2, each 32x32 out.
__global__ __launch_bounds__(256) void gemm_bt_kernel(
        const unsigned short* __restrict__ A,
        const unsigned short* __restrict__ Bt,
        void* __restrict__ Cout,
        unsigned short* __restrict__ VtOut,
        int M, int N, int K, int out_bf16) {
    __shared__ unsigned short ldsA[2][64 * 64];
    __shared__ unsigned short ldsB[2][64 * 64];
    int lane = threadIdx.x & 63, wave = threadIdx.x >> 6;
    int ln = lane & 15, quad = lane >> 4;
    int wm = wave >> 1, wn = wave & 1;
    int m0 = blockIdx.y * 64, n0 = blockIdx.x * 64;

    int t = threadIdx.x;
    int trow = t >> 3, tcb = t & 7;
    int gcb = tcb ^ (trow & 7);
    const unsigned short* gA = A + (size_t)(m0 + trow) * K + gcb * 8;
    const unsigned short* gA2 = gA + (size_t)32 * K;
    const unsigned short* gB = Bt + (size_t)(n0 + trow) * K + gcb * 8;
    const unsigned short* gB2 = gB + (size_t)32 * K;
    int dst = t * 8;   // shorts; rr=1 adds 2048

    auto stage = [&](int k0, int buf) {
        gload16(gA + k0, &ldsA[buf][dst]);
        gload16(gA2 + k0, &ldsA[buf][dst + 2048]);
        gload16(gB + k0, &ldsB[buf][dst]);
        gload16(gB2 + k0, &ldsB[buf][dst + 2048]);
    };

    f32x4 acc[2][2];
    for (int i = 0; i < 2; ++i)
        for (int jj = 0; jj < 2; ++jj) acc[i][jj] = f32x4{0, 0, 0, 0};

    stage(0, 0);
    int niter = K >> 6;
    for (int it = 0; it < niter; ++it) {
        __syncthreads();
        if (it + 1 < niter) stage((it + 1) << 6, (it + 1) & 1);
        const unsigned short* La = ldsA[it & 1];
        const unsigned short* Lb = ldsB[it & 1];
        short8 aF[2][2], bF[2][2];
#pragma unroll
        for (int hh = 0; hh < 2; ++hh) {
            int kc = hh * 4 + quad;
#pragma unroll
            for (int mt = 0; mt < 2; ++mt)
                aF[hh][mt] = *(const short8*)&La[(wm * 32 + mt * 16 + ln) * 64 +
                                                ((kc ^ (ln & 7)) * 8)];
#pragma unroll
            for (int nt = 0; nt < 2; ++nt)
                bF[hh][nt] = *(const short8*)&Lb[(wn * 32 + nt * 16 + ln) * 64 +
                                                ((kc ^ (ln & 7)) * 8)];
        }
#pragma unroll
        for (int hh = 0; hh < 2; ++hh)
#pragma unroll
            for (int mt = 0; mt < 2; ++mt)
#pragma unroll
                for (int nt = 0; nt < 2; ++nt)
                    acc[mt][nt] = __builtin_amdgcn_mfma_f32_16x16x32_bf16(
                        aF[hh][mt], bF[hh][nt], acc[mt][nt], 0, 0, 0);
    }

    if (out_bf16) {
        unsigned short* C = (unsigned short*)Cout;
#pragma unroll
        for (int mt = 0; mt < 2; ++mt)
            for (int nt = 0; nt < 2; ++nt)
                for (int r = 0; r < 4; ++r) {
                    int row = m0 + wm * 32 + mt * 16 + quad * 4 + r;
                    int col = n0 + wn * 32 + nt * 16 + ln;
                    C[(size_t)row * N + col] = f2bf(acc[mt][nt][r]);
                }
        if (VtOut != nullptr && n0 == DM + HD) {   // V block: also write transposed
#pragma unroll
            for (int mt = 0; mt < 2; ++mt)
                for (int nt = 0; nt < 2; ++nt)
                    for (int r = 0; r < 4; ++r) {
                        int row = m0 + wm * 32 + mt * 16 + quad * 4 + r;
                        int d = wn * 32 + nt * 16 + ln;          // 0..63
                        int bb = row >> 11, s = row & 2047;
                        VtOut[((size_t)bb * HD + d) * SEQ + s] = f2bf(acc[mt][nt][r]);
                    }
        }
    } else {
        float* C = (float*)Cout;
#pragma unroll
        for (int mt = 0; mt < 2; ++mt)
            for (int nt = 0; nt < 2; ++nt)
                for (int r = 0; r < 4; ++r) {
                    int row = m0 + wm * 32 + mt * 16 + quad * 4 + r;
                    int col = n0 + wn * 32 + nt * 16 + ln;
                    C[(size_t)row * N + col] = acc[mt][nt][r];
                }
    }
}

// ---------------- flash attention (multi-query, causal) ----------------
// Operand-swapped, register-resident P:
//   S^T = K . Q^T -> C-layout gives P^T[key=c*16+quad*4+r][q=ln] per lane.
//   PV: O^T = V^T . P^T; the P^T B-fragment (lane needs keys quad*8..+7,
//   i.e. sub-tile cs=quad>>1 from source lanes quad'=(quad&1)*2+{0,1}) is
//   assembled in registers. NOTE __shfl(var, src) evaluates var ON THE
//   SOURCE LANE, and one source lane serves different cs to different
//   destination quads -> must shuffle BOTH packed sub-tiles and select at
//   the destination (8 shfl + 4 cndmask per 32-key window). [R8 bug: the
//   source-side select delivered cs=quad&1 instead of quad>>1.]
// K(64x64) + Vt(64x64) double-buffered via global_load_lds, (row&7) xor
// swizzle. 4 waves share tiles; wave w owns q-tile jg*4+w (jg full steps +
// 1 partial). lsum: one scalar/lane (q=ln), quad-reduced in the epilogue.
__global__ __launch_bounds__(256) void attn_kernel(
        const unsigned short* __restrict__ QKV,
        const unsigned short* __restrict__ Vt,
        unsigned short* __restrict__ Y) {
    __shared__ unsigned short ldsK[2][64 * 64];
    __shared__ unsigned short ldsV[2][64 * 64];

    int lane = threadIdx.x & 63, wave = threadIdx.x >> 6;
    int ln = lane & 15, quad = lane >> 4;
    int bid = blockIdx.x;
    int jg = 31 - (bid >> 5);             // heavy-first
    int bh = bid & 31;
    int h = bh & 15, b = bh >> 4;
    int q0 = (jg * 4 + wave) * 16;
    const size_t baseRow = (size_t)b * SEQ;
    const unsigned short* Vb = Vt + (size_t)b * HD * SEQ;

    int t = threadIdx.x;
    int trow = t >> 3, tcb = t & 7;
    int cbg = tcb ^ (trow & 7);
    const unsigned short* gK = QKV + (baseRow + trow) * LDQ + DM + cbg * 8;
    const unsigned short* gV = Vb + (size_t)trow * SEQ + cbg * 8;
    int dstoff = trow * 64 + tcb * 8;

    auto stageKV = [&](int s0n, int buf) {
#pragma unroll
        for (int rr = 0; rr < 2; ++rr) {
            gload16(gK + (size_t)(s0n + 32 * rr) * LDQ, &ldsK[buf][dstoff + rr * 2048]);
            gload16(gV + (size_t)32 * rr * SEQ + s0n,   &ldsV[buf][dstoff + rr * 2048]);
        }
    };

    // Q fragments (B-operand layout: [q=ln][hd=quad*8+j])
    short8 aQ0, aQ1;
    {
        const unsigned short* qp = QKV + (baseRow + q0 + ln) * LDQ + h * HD + quad * 8;
        aQ0 = *(const short8*)(qp);
        aQ1 = *(const short8*)(qp + 32);
    }

    float lsum = 0.f;
    f32x4 o[4];                            // O^T[d=nt*16+quad*4+r][q=ln]
    for (int nt = 0; nt < 4; ++nt) o[nt] = f32x4{0, 0, 0, 0};

    const float c_exp = 0.1803368802f;     // 0.125 * log2(e)
    const int myq = q0 + ln;
    const int srcl = (quad & 1) * 32 + ln; // shuffle source lane base
    const bool hi_cs = (quad >= 2);        // destination-side sub-tile select

    auto computeStep = [&](int s0, int buf, bool partial) {
        const unsigned short* Kb = ldsK[buf];
        const unsigned short* Vf = ldsV[buf];
#pragma unroll
        for (int w2 = 0; w2 < 2; ++w2) {   // two 32-key windows
            if (partial && (w2 * 32 > wave * 16 + 15)) continue;  // wave-uniform
            unsigned pk[2][2];             // [sub-tile cs][packed p01 / p23]
#pragma unroll
            for (int cs = 0; cs < 2; ++cs) {
                int c = w2 * 2 + cs;
                if (partial && c > wave) { pk[cs][0] = 0; pk[cs][1] = 0; continue; }
                int kbase = s0 + c * 16;
                short8 kf0 = *(const short8*)&Kb[(c * 16 + ln) * 64 + ((quad ^ (ln & 7)) * 8)];
                short8 kf1 = *(const short8*)&Kb[(c * 16 + ln) * 64 + (((4 + quad) ^ (ln & 7)) * 8)];
                f32x4 s = {0, 0, 0, 0};
                s = __builtin_amdgcn_mfma_f32_16x16x32_bf16(kf0, aQ0, s, 0, 0, 0);
                s = __builtin_amdgcn_mfma_f32_16x16x32_bf16(kf1, aQ1, s, 0, 0, 0);
                bool diag = partial && (c == wave);
                float p[4];
#pragma unroll
                for (int r = 0; r < 4; ++r) {
                    float e = __builtin_exp2f(s[r] * c_exp);
                    if (diag && (kbase + quad * 4 + r > myq)) e = 0.f;  // causal
                    p[r] = e;
                    lsum += e;
                }
                pk[cs][0] = (__float_as_uint(p[0]) >> 16) |
                            (__float_as_uint(p[1]) & 0xffff0000u);
                pk[cs][1] = (__float_as_uint(p[2]) >> 16) |
                            (__float_as_uint(p[3]) & 0xffff0000u);
            }
            // assemble P^T B-fragment: shuffle BOTH sub-tiles, select at dest
            unsigned a00 = (unsigned)__shfl((int)pk[0][0], srcl);
            unsigned a10 = (unsigned)__shfl((int)pk[1][0], srcl);
            unsigned a01 = (unsigned)__shfl((int)pk[0][1], srcl);
            unsigned a11 = (unsigned)__shfl((int)pk[1][1], srcl);
            unsigned b00 = (unsigned)__shfl((int)pk[0][0], srcl + 16);
            unsigned b10 = (unsigned)__shfl((int)pk[1][0], srcl + 16);
            unsigned b01 = (unsigned)__shfl((int)pk[0][1], srcl + 16);
            unsigned b11 = (unsigned)__shfl((int)pk[1][1], srcl + 16);
            union { unsigned u[4]; short8 v; } bP;
            bP.u[0] = hi_cs ? a10 : a00;
            bP.u[1] = hi_cs ? a11 : a01;
            bP.u[2] = hi_cs ? b10 : b00;
            bP.u[3] = hi_cs ? b11 : b01;
            // O^T += V^T . P^T
#pragma unroll
            for (int nt = 0; nt < 4; ++nt) {
                short8 vA = *(const short8*)&Vf[(nt * 16 + ln) * 64 +
                                               (((w2 * 4 + quad) ^ (ln & 7)) * 8)];
                o[nt] = __builtin_amdgcn_mfma_f32_16x16x32_bf16(vA, bP.v, o[nt], 0, 0, 0);
            }
        }
    };

    stageKV(0, 0);
    for (int it = 0; it < jg; ++it) {          // full steps, mask-free
        __syncthreads();
        stageKV((it + 1) * 64, (it + 1) & 1);
        computeStep(it * 64, it & 1, false);
    }
    __syncthreads();
    computeStep(jg * 64, jg & 1, true);        // the one partial step

    // epilogue: l lives per-lane (q=ln); sum the 4 quads, then Y = O / l
    lsum += __shfl_xor(lsum, 16);
    lsum += __shfl_xor(lsum, 32);
    float inv = 1.0f / lsum;
    unsigned short* yp = Y + (baseRow + q0 + ln) * DM + h * HD + quad * 4;
#pragma unroll
    for (int nt = 0; nt < 4; ++nt) {
        ushort4 w;
        w.x = f2bf(o[nt][0] * inv);
        w.y = f2bf(o[nt][1] * inv);
        w.z = f2bf(o[nt][2] * inv);
        w.w = f2bf(o[nt][3] * inv);
        *(ushort4*)(yp + nt * 16) = w;
    }
}

extern "C" void kernel_launch(void* const* d_in, const int* in_sizes, int n_in,
                              void* d_out, int out_size, void* d_ws, size_t ws_size,
                              hipStream_t stream) {
    const float* x  = (const float*)d_in[0];
    const float* Wq = (const float*)d_in[1];
    const float* Wk = (const float*)d_in[2];
    const float* Wv = (const float*)d_in[3];
    const float* Wo = (const float*)d_in[4];
    float* out = (float*)d_out;

    char* ws = (char*)d_ws;
    // workspace (22.8 MB): slot0 is xb until qkv-gemm completes, then y.
    unsigned short* xb  = (unsigned short*)(ws);                // 4096x1024 bf16 (8 MB)
    unsigned short* y   = (unsigned short*)(ws);                // alias: attn out
    unsigned short* wtq = (unsigned short*)(ws + 8388608);      // 1152x1024 bf16
    unsigned short* wot = (unsigned short*)(ws + 10747904);     // 1024x1024 bf16
    unsigned short* qkv = (unsigned short*)(ws + 12845056);     // 4096x1152 bf16
    unsigned short* Vt  = (unsigned short*)(ws + 22282240);     // 2x64x2048 bf16 (0.5 MB)

    const int BT = BATCH * SEQ;  // 4096 rows

    hipLaunchKernelGGL(cast_x_kernel, dim3(BT * DM / 4 / 256), dim3(256), 0, stream,
                       x, xb, BT * DM);
    hipLaunchKernelGGL(prep_w_kernel, dim3(DM / 32, DM / 32, 4), dim3(256), 0, stream,
                       Wq, Wk, Wv, Wo, wtq, wot);

    // QKV = x @ [Wq|Wk|Wv] -> bf16; V block also written transposed to Vt
    hipLaunchKernelGGL(gemm_bt_kernel, dim3(LDQ / 64, BT / 64), dim3(256), 0, stream,
                       xb, wtq, (void*)qkv, Vt, BT, LDQ, DM, 1);

    // flash attention (register-resident P) -> y bf16 (overwrites xb, now dead)
    hipLaunchKernelGGL(attn_kernel, dim3(32 * 32), dim3(256), 0, stream,
                       qkv, Vt, y);

    // out = y @ Wo -> fp32
    hipLaunchKernelGGL(gemm_bt_kernel, dim3(DM / 64, BT / 64), dim3(256), 0, stream,
                       y, wot, (void*)out, nullptr, BT, DM, DM, 0);
}